// Round 4
// baseline (290.605 us; speedup 1.0000x reference)
//
#include <hip/hip_runtime.h>

// CVRP decoder v4, MI355X.
// v4: proj GEMMs hoist all A-fragments into VGPRs before the K-loop (no
// global latency inside the MFMA loop, no in-loop barriers); attn reuses
// staged K/V across 2 p-tiles; s2 phase-2 runs 4 interleaved early-exit
// binary searches with all dist/ninf loads hoisted.
// Swizzle: (row,k): granule g=k>>3 stored at pos=(g&~7)|((g&7)^(row&7)).

typedef unsigned short u16;
typedef unsigned int u32;
typedef unsigned long long u64;
typedef __attribute__((ext_vector_type(8))) short short8;
typedef __attribute__((ext_vector_type(4))) float f32x4;
typedef __attribute__((ext_vector_type(16))) float f32x16;
typedef __attribute__((ext_vector_type(4))) u32 u32x4;
typedef __attribute__((ext_vector_type(8))) u16 u16x8;

#define AS1U(p) ((const __attribute__((address_space(1))) u32*)(p))
#define AS3U(p) ((__attribute__((address_space(3))) u32*)(p))

#define QSCALE (0.25f * 1.44269504088896340736f)  // 1/sqrt(D) * log2(e)
#define LOG2E 1.44269504088896340736f
#define INV_SQRT2 0.70710678118654752440f

__device__ __forceinline__ u16 f2bf(float f) {
  u32 u = __builtin_bit_cast(u32, f);
  return (u16)((u + 0x7FFFu + ((u >> 16) & 1u)) >> 16);  // RNE
}

__device__ __forceinline__ u32 pack_bf(float a, float b) {
  u32 ua = __builtin_bit_cast(u32, a), ub = __builtin_bit_cast(u32, b);
  ua = ua + 0x7FFFu + ((ua >> 16) & 1u);
  ub = ub + 0x7FFFu + ((ub >> 16) & 1u);
  return __builtin_amdgcn_perm(ub, ua, 0x07060302u);
}

__device__ __forceinline__ u32 swz_off(u32 row, u32 k) {  // half-index
  u32 g = k >> 3;
  u32 pos = (g & ~7u) | ((g & 7u) ^ (row & 7u));
  return row * 256u + pos * 8u + (k & 7u);
}

__device__ __forceinline__ float fast_tanh(float x) {
  float e = __builtin_amdgcn_exp2f(x * (2.0f * LOG2E));
  return 1.0f - 2.0f * __builtin_amdgcn_rcpf(e + 1.0f);
}

// ---------------------------------------------------------------------------
// convert: fp32 -> bf16, one 8-element granule per thread, swizzled rows.
// ---------------------------------------------------------------------------
__global__ __launch_bounds__(256) void convert_kernel(
    const float* __restrict__ nodes, const float* __restrict__ last,
    const float* __restrict__ Wk, const float* __restrict__ Wv,
    const float* __restrict__ Wq, const float* __restrict__ Wc,
    u16* __restrict__ nodes_bf, u16* __restrict__ last_bf,
    u16* __restrict__ Wkv_bf, u16* __restrict__ Wq_bf,
    float* __restrict__ wq_last, u16* __restrict__ Wc_bf) {
  long i = (long)blockIdx.x * 256 + threadIdx.x;
  if (i < 524288) {  // nodes: 16384 rows x 32 granules
    u32 row = (u32)(i >> 5), g = (u32)(i & 31);
    const float4* s4 = (const float4*)nodes + i * 2;
    float4 v0 = s4[0], v1 = s4[1];
    u16x8 o = {f2bf(v0.x), f2bf(v0.y), f2bf(v0.z), f2bf(v0.w),
               f2bf(v1.x), f2bf(v1.y), f2bf(v1.z), f2bf(v1.w)};
    u32 pos = (g & ~7u) | ((g & 7u) ^ (row & 7u));
    *(u16x8*)(nodes_bf + row * 256 + pos * 8) = o;
  } else if (i < 1048576) {  // last
    long j = i - 524288;
    u32 row = (u32)(j >> 5), g = (u32)(j & 31);
    const float4* s4 = (const float4*)last + j * 2;
    float4 v0 = s4[0], v1 = s4[1];
    u16x8 o = {f2bf(v0.x), f2bf(v0.y), f2bf(v0.z), f2bf(v0.w),
               f2bf(v1.x), f2bf(v1.y), f2bf(v1.z), f2bf(v1.w)};
    u32 pos = (g & ~7u) | ((g & 7u) ^ (row & 7u));
    *(u16x8*)(last_bf + row * 256 + pos * 8) = o;
  } else if (i < 1064960) {  // Wkv: 512 rows (Wk | Wv)
    long j = i - 1048576;
    u32 row = (u32)(j >> 5), g = (u32)(j & 31);
    const float* src = (row < 256) ? (Wk + row * 256 + g * 8)
                                   : (Wv + (row - 256) * 256 + g * 8);
    u16x8 o;
    for (int q = 0; q < 8; q++) o[q] = f2bf(src[q]);
    u32 pos = (g & ~7u) | ((g & 7u) ^ (row & 7u));
    *(u16x8*)(Wkv_bf + row * 256 + pos * 8) = o;
  } else if (i < 1073152) {  // Wq main 256x256 (src stride 257)
    long j = i - 1064960;
    u32 row = (u32)(j >> 5), g = (u32)(j & 31);
    const float* src = Wq + row * 257 + g * 8;
    u16x8 o;
    for (int q = 0; q < 8; q++) o[q] = f2bf(src[q]);
    u32 pos = (g & ~7u) | ((g & 7u) ^ (row & 7u));
    *(u16x8*)(Wq_bf + row * 256 + pos * 8) = o;
  } else if (i < 1081344) {  // Wc 256x256
    long j = i - 1073152;
    u32 row = (u32)(j >> 5), g = (u32)(j & 31);
    const float* src = Wc + row * 256 + g * 8;
    u16x8 o;
    for (int q = 0; q < 8; q++) o[q] = f2bf(src[q]);
    u32 pos = (g & ~7u) | ((g & 7u) ^ (row & 7u));
    *(u16x8*)(Wc_bf + row * 256 + pos * 8) = o;
  } else if (i < 1081600) {  // Wq last column (fp32)
    long o = i - 1081344;
    wq_last[o] = Wq[o * 257 + 256];
  }
}

// ---------------------------------------------------------------------------
// proj core v4: block = 64m x 64j, K=256. All 16 A-frags (64 VGPR) hoisted
// to registers up front; W j-tile (64x256, 32KB) DMA-staged once; single
// barrier; K-loop is pure ds_read + MFMA. Wave (2x2): 32m x 32j.
// ---------------------------------------------------------------------------
__device__ __forceinline__ void proj_core(
    const u16* __restrict__ Abase, const u16* __restrict__ Wbase,
    u16* Ws, f32x4 acc[2][2]) {
  const int t = threadIdx.x;
  const int lane = t & 63, w = t >> 6;
  const int wm = (w & 1) * 32, wj = (w >> 1) * 32;
  const int qq = lane >> 4, lr = lane & 15;
  short8 af[2][8];
#pragma unroll
  for (int kt = 0; kt < 8; ++kt) {
    int g = kt * 4 + qq;
    int pos = (g & ~7) | ((g & 7) ^ (lr & 7));
#pragma unroll
    for (int ms = 0; ms < 2; ++ms)
      af[ms][kt] = *(const short8*)(Abase + (wm + ms * 16 + lr) * 256 + pos * 8);
  }
#pragma unroll
  for (int c = 0; c < 8; ++c)
    __builtin_amdgcn_global_load_lds(AS1U(Wbase + c * 2048 + t * 8),
                                     AS3U(Ws + c * 2048 + w * 512), 16, 0, 0);
  acc[0][0] = (f32x4){0.f, 0.f, 0.f, 0.f};
  acc[0][1] = (f32x4){0.f, 0.f, 0.f, 0.f};
  acc[1][0] = (f32x4){0.f, 0.f, 0.f, 0.f};
  acc[1][1] = (f32x4){0.f, 0.f, 0.f, 0.f};
  __syncthreads();
#pragma unroll
  for (int kt = 0; kt < 8; ++kt) {
    int g = kt * 4 + qq;
    int pos = (g & ~7) | ((g & 7) ^ (lr & 7));
    short8 b0 = *(const short8*)(Ws + (wj + lr) * 256 + pos * 8);
    short8 b1 = *(const short8*)(Ws + (wj + 16 + lr) * 256 + pos * 8);
    acc[0][0] = __builtin_amdgcn_mfma_f32_16x16x32_bf16(af[0][kt], b0, acc[0][0], 0, 0, 0);
    acc[0][1] = __builtin_amdgcn_mfma_f32_16x16x32_bf16(af[0][kt], b1, acc[0][1], 0, 0, 0);
    acc[1][0] = __builtin_amdgcn_mfma_f32_16x16x32_bf16(af[1][kt], b0, acc[1][0], 0, 0, 0);
    acc[1][1] = __builtin_amdgcn_mfma_f32_16x16x32_bf16(af[1][kt], b1, acc[1][1], 0, 0, 0);
  }
}

// K|V projection. K out: per (b,h) chunk layout [nch32][2][32][8]; V out:
// [bh][d][n] XOR-swizzled on n.
__global__ __launch_bounds__(256) void gemm_kv_kernel(
    const u16* __restrict__ nodes_bf, const u16* __restrict__ Wkv,
    u16* __restrict__ Kbuf, u16* __restrict__ Vbuf) {
  __shared__ __attribute__((aligned(16))) u16 Ws[16384];
  int bx = blockIdx.x;
  int jt = bx & 7, mt = (bx >> 3) & 7, b = bx >> 6;
  f32x4 acc[2][2];
  proj_core(nodes_bf + (b * 512 + mt * 64) * 256, Wkv + jt * 64 * 256, Ws, acc);
  int t = threadIdx.x, lane = t & 63, w = t >> 6;
  int wm = (w & 1) * 32, wj = (w >> 1) * 32, qq = lane >> 4, lr = lane & 15;
  for (int ms = 0; ms < 2; ++ms)
    for (int fj = 0; fj < 2; ++fj) {
      int j = jt * 64 + wj + fj * 16 + lr;
      for (int r = 0; r < 4; ++r) {
        int n = mt * 64 + wm + ms * 16 + qq * 4 + r;
        u16 val = f2bf(acc[ms][fj][r]);
        if (j < 256) {
          int h = j >> 4, d = j & 15;
          Kbuf[(u32)(b * 16 + h) * 8192 + (u32)(n >> 5) * 512 +
               (u32)(d >> 3) * 256 + (u32)(n & 31) * 8 + (u32)(d & 7)] = val;
        } else {
          int o = j - 256, h = o >> 4, d = o & 15;
          u32 G = (u32)(n >> 3);
          u32 pos = (G & ~7u) | ((G & 7u) ^ ((u32)d & 7u));
          Vbuf[(u32)(b * 16 + h) * 8192 + (u32)d * 512 + pos * 8 + (u32)(n & 7)] = val;
        }
      }
    }
}

// Q projection -> Qbuf [bh][p][16], pre-scaled by 0.25*log2e, +load*wq_last.
__global__ __launch_bounds__(256) void gemm_q_kernel(
    const u16* __restrict__ last_bf, const u16* __restrict__ Wqm,
    const float* __restrict__ wq_last, const float* __restrict__ loadv,
    u16* __restrict__ Qbuf) {
  __shared__ __attribute__((aligned(16))) u16 Ws[16384];
  int bx = blockIdx.x;
  int jt = bx & 3, mt = (bx >> 2) & 7, b = bx >> 5;
  f32x4 acc[2][2];
  proj_core(last_bf + (b * 512 + mt * 64) * 256, Wqm + jt * 64 * 256, Ws, acc);
  int t = threadIdx.x, lane = t & 63, w = t >> 6;
  int wm = (w & 1) * 32, wj = (w >> 1) * 32, qq = lane >> 4, lr = lane & 15;
  for (int ms = 0; ms < 2; ++ms)
    for (int fj = 0; fj < 2; ++fj) {
      int o = jt * 64 + wj + fj * 16 + lr;
      float wql = wq_last[o];
      for (int r = 0; r < 4; ++r) {
        int p = mt * 64 + wm + ms * 16 + qq * 4 + r;
        float ld = loadv[b * 512 + p];
        float v = (acc[ms][fj][r] + ld * wql) * QSCALE;
        Qbuf[((b * 16 + (o >> 4)) * 512 + p) * 16 + (o & 15)] = f2bf(v);
      }
    }
}

// ---------------------------------------------------------------------------
// Attention: one (b,h, half) per block; staged K/V reused across 2 p-tiles
// of 128 (wave = 32 Q-rows per tile). S^T = K*Q^T via mfma_32x32x16; P
// relayout in registers (shfl_xor 32 + cndmask); exp2, no max-subtraction.
// ---------------------------------------------------------------------------
__global__ __launch_bounds__(256) void attn_kernel(
    const u16* __restrict__ Qb, const u16* __restrict__ Kb,
    const u16* __restrict__ Vb, u16* __restrict__ Ob) {
  __shared__ __attribute__((aligned(16))) u16 Ks[8192];
  __shared__ __attribute__((aligned(16))) u16 Vt[8192];
  int bx = blockIdx.x;
  int pt = bx & 1, bh = bx >> 1;
  int t = threadIdx.x, lane = t & 63, w = t >> 6;
  int lo5 = lane & 31, hi = lane >> 5;
  int vd = lane & 15;
  for (int c = 0; c < 4; ++c) {
    __builtin_amdgcn_global_load_lds(AS1U(Kb + bh * 8192 + c * 2048 + t * 8),
                                     AS3U(Ks + c * 2048 + w * 512), 16, 0, 0);
    __builtin_amdgcn_global_load_lds(AS1U(Vb + bh * 8192 + c * 2048 + t * 8),
                                     AS3U(Vt + c * 2048 + w * 512), 16, 0, 0);
  }
  __syncthreads();
  int b = bh >> 4, h = bh & 15;
  for (int pp = 0; pp < 2; ++pp) {
    int p0 = pt * 256 + pp * 128 + w * 32;
    short8 qf = *(const short8*)(Qb + bh * 8192 + (p0 + lo5) * 16 + hi * 8);
    f32x16 oacc = {};
    float lsum = 0.f;
    for (int it = 0; it < 16; ++it) {
      short8 kf = *(const short8*)(Ks + it * 512 + lane * 8);
      f32x16 st = __builtin_amdgcn_mfma_f32_32x32x16_bf16(kf, qf, (f32x16){}, 0, 0, 0);
      float ev[16];
      float ls = 0.f;
#pragma unroll
      for (int r = 0; r < 16; ++r) ev[r] = __builtin_amdgcn_exp2f(st[r]);
#pragma unroll
      for (int r = 0; r < 16; ++r) ls += ev[r];
      lsum += ls;
      u32 pk[8], pd[8];
#pragma unroll
      for (int q = 0; q < 8; ++q) pk[q] = pack_bf(ev[2 * q], ev[2 * q + 1]);
#pragma unroll
      for (int q = 0; q < 8; ++q) pd[q] = (u32)__shfl_xor((int)pk[q], 32, 64);
      bool h1 = (hi != 0);
      u32x4 a1u = {h1 ? pd[2] : pk[0], h1 ? pd[3] : pk[1],
                   h1 ? pk[2] : pd[0], h1 ? pk[3] : pd[1]};
      u32x4 a2u = {h1 ? pd[6] : pk[4], h1 ? pd[7] : pk[5],
                   h1 ? pk[6] : pd[4], h1 ? pk[7] : pd[5]};
      short8 A1 = __builtin_bit_cast(short8, a1u);
      short8 A2 = __builtin_bit_cast(short8, a2u);
      int G1 = it * 4 + hi, G2 = G1 + 2;
      short8 v1 = *(const short8*)(Vt + vd * 512 + (((G1 & ~7) | ((G1 & 7) ^ (vd & 7)))) * 8);
      short8 v2 = *(const short8*)(Vt + vd * 512 + (((G2 & ~7) | ((G2 & 7) ^ (vd & 7)))) * 8);
      oacc = __builtin_amdgcn_mfma_f32_32x32x16_bf16(A1, v1, oacc, 0, 0, 0);
      oacc = __builtin_amdgcn_mfma_f32_32x32x16_bf16(A2, v2, oacc, 0, 0, 0);
    }
    lsum += __shfl_xor(lsum, 32, 64);
    float inv = __builtin_amdgcn_rcpf(lsum);
    float iv[16];
#pragma unroll
    for (int r = 0; r < 16; ++r) {
      int pl = (r & 3) + 8 * (r >> 2) + 4 * hi;
      iv[r] = __shfl(inv, pl, 64);
    }
    if (lo5 < 16) {
#pragma unroll
      for (int r = 0; r < 16; ++r) {
        int pl = (r & 3) + 8 * (r >> 2) + 4 * hi;
        u32 row = (u32)(b * 512 + p0 + pl);
        u32 k = (u32)(h * 16 + lo5);
        Ob[swz_off(row, k)] = f2bf(oacc[r] * iv[r]);
      }
    }
  }
}

// C-projection: mh = (O @ Wc^T + bias)/16, written row-swizzled.
__global__ __launch_bounds__(256) void gemm_c_kernel(
    const u16* __restrict__ Obuf, const u16* __restrict__ Wcm,
    const float* __restrict__ Wcb, u16* __restrict__ mh_bf) {
  __shared__ __attribute__((aligned(16))) u16 Ws[16384];
  int bx = blockIdx.x;
  int jt = bx & 3, mt = (bx >> 2) & 7, b = bx >> 5;
  f32x4 acc[2][2];
  proj_core(Obuf + (b * 512 + mt * 64) * 256, Wcm + jt * 64 * 256, Ws, acc);
  int t = threadIdx.x, lane = t & 63, w = t >> 6;
  int wm = (w & 1) * 32, wj = (w >> 1) * 32, qq = lane >> 4, lr = lane & 15;
  for (int ms = 0; ms < 2; ++ms)
    for (int fj = 0; fj < 2; ++fj) {
      int e = jt * 64 + wj + fj * 16 + lr;
      float bias = Wcb[e];
      for (int r = 0; r < 4; ++r) {
        int p = mt * 64 + wm + ms * 16 + qq * 4 + r;
        mh_bf[swz_off((u32)(b * 512 + p), (u32)e)] = f2bf((acc[ms][fj][r] + bias) * 0.0625f);
      }
    }
}

// ---------------------------------------------------------------------------
// Fused score2 GEMM + topk(100 smallest) + penalty + tanh-clip + ninf +
// softmax. Block = 16 rows x 512 cols. Phase 2: all dist/ninf loads hoisted,
// 4 interleaved binary searches with exact-count early exit.
// ---------------------------------------------------------------------------
__global__ __launch_bounds__(256) void s2_fused_kernel(
    const u16* __restrict__ mh_bf, const u16* __restrict__ nodes_bf,
    const float* __restrict__ cdist, const float* __restrict__ ninf,
    float* __restrict__ out) {
  __shared__ float lg[16][516];
  int bx = blockIdx.x;
  int ptile = bx & 31, b = bx >> 5;
  int t = threadIdx.x, lane = t & 63, w = t >> 6;
  int qq = lane >> 4, lr = lane & 15;
  // hoisted A-fragments (16 rows x 256 k) from swizzled global
  short8 afr[8];
  const u16* Abase = mh_bf + (u32)(b * 512 + ptile * 16) * 256;
#pragma unroll
  for (int kt = 0; kt < 8; ++kt) {
    int g = kt * 4 + qq;
    int pos = (g & ~7) | ((g & 7) ^ (lr & 7));
    afr[kt] = *(const short8*)(Abase + lr * 256 + pos * 8);
  }
  // GEMM: wave w owns cols [w*128, w*128+128), B direct from global (L2-hot)
  const u16* Bbase = nodes_bf + (u32)b * 512 * 256;
#pragma unroll
  for (int nti = 0; nti < 8; ++nti) {
    int nt = w * 8 + nti;
    f32x4 acc = {0.f, 0.f, 0.f, 0.f};
#pragma unroll
    for (int kt = 0; kt < 8; ++kt) {
      int g = kt * 4 + qq;
      int pos = (g & ~7) | ((g & 7) ^ (lr & 7));
      short8 bfv = *(const short8*)(Bbase + (nt * 16 + lr) * 256 + pos * 8);
      acc = __builtin_amdgcn_mfma_f32_16x16x32_bf16(afr[kt], bfv, acc, 0, 0, 0);
    }
#pragma unroll
    for (int r = 0; r < 4; ++r) lg[qq * 4 + r][nt * 16 + lr] = acc[r];
  }
  __syncthreads();
  // phase 2: wave owns rows [w*4, w*4+4); all loads hoisted, searches ILP'd
  long grow0 = (long)b * 512 + ptile * 16 + w * 4;
  u32 u[4][8];
#pragma unroll
  for (int rr = 0; rr < 4; ++rr) {
    const u32* du = (const u32*)(cdist + (grow0 + rr) * 512);
#pragma unroll
    for (int i = 0; i < 8; ++i) u[rr][i] = du[i * 64 + lane];
  }
  float nf[4][8];
#pragma unroll
  for (int rr = 0; rr < 4; ++rr) {
    const float* nr = ninf + (grow0 + rr) * 512;
#pragma unroll
    for (int i = 0; i < 8; ++i) nf[rr][i] = nr[i * 64 + lane];
  }
  u32 lo[4] = {0u, 0u, 0u, 0u};
  u32 hi[4] = {0x3F800000u, 0x3F800000u, 0x3F800000u, 0x3F800000u};
  u32 T[4];
  u32 donemask = 0, simple = 0;
  for (int iter = 0; iter < 32; ++iter) {
    if (donemask == 15u) break;
#pragma unroll
    for (int rr = 0; rr < 4; ++rr) {
      if (donemask & (1u << rr)) continue;  // wave-uniform
      u32 mid = lo[rr] + ((hi[rr] - lo[rr]) >> 1);
      int cnt = 0;
#pragma unroll
      for (int i = 0; i < 8; ++i) cnt += __popcll(__ballot(u[rr][i] <= mid));
      if (cnt == 100) {  // exact: mask u<=mid IS the top-100 set (no tie risk)
        T[rr] = mid; donemask |= 1u << rr; simple |= 1u << rr;
      } else {
        if (cnt > 100) hi[rr] = mid; else lo[rr] = mid + 1;
        if (lo[rr] >= hi[rr]) { T[rr] = lo[rr]; donemask |= 1u << rr; }
      }
    }
  }
  u64 lm = (1ull << lane) - 1ull;
#pragma unroll
  for (int rr = 0; rr < 4; ++rr) {
    long grow = grow0 + rr;
    bool smp = (simple >> rr) & 1u;  // wave-uniform
    u32 Tr = T[rr];
    int quota = 0, eqacc = 0;
    if (!smp) {
      int cl = 0;
#pragma unroll
      for (int i = 0; i < 8; ++i) cl += __popcll(__ballot(u[rr][i] < Tr));
      quota = 100 - cl;
    }
    float ex[8];
    float s = 0.f;
#pragma unroll
    for (int i = 0; i < 8; ++i) {
      bool sel;
      if (smp) {
        sel = (u[rr][i] <= Tr);
      } else {
        u64 e = __ballot(u[rr][i] == Tr);
        sel = (u[rr][i] < Tr) ||
              ((u[rr][i] == Tr) && ((eqacc + __popcll(e & lm)) < quota));
        eqacc += __popcll(e);
      }
      float dvv = __builtin_bit_cast(float, u[rr][i]);
      float x = lg[w * 4 + rr][i * 64 + lane] + (sel ? -dvv * INV_SQRT2 : 1.0f);
      float lgt = 10.0f * fast_tanh(x) + nf[rr][i];
      ex[i] = __builtin_amdgcn_exp2f(lgt * LOG2E);
      s += ex[i];
    }
    for (int m = 1; m < 64; m <<= 1) s += __shfl_xor(s, m, 64);
    float inv = 1.0f / s;
    float* orow = out + grow * 512;
#pragma unroll
    for (int i = 0; i < 8; ++i) orow[i * 64 + lane] = ex[i] * inv;
  }
}

// ---------------------------------------------------------------------------
extern "C" void kernel_launch(void* const* d_in, const int* in_sizes, int n_in,
                              void* d_out, int out_size, void* d_ws, size_t ws_size,
                              hipStream_t stream) {
  const float* nodes = (const float*)d_in[0];
  const float* last  = (const float*)d_in[1];
  const float* loadv = (const float*)d_in[2];
  const float* cdist = (const float*)d_in[3];
  const float* ninf  = (const float*)d_in[6];
  const float* Wq    = (const float*)d_in[7];
  const float* Wk    = (const float*)d_in[8];
  const float* Wv    = (const float*)d_in[9];
  const float* Wc    = (const float*)d_in[10];
  const float* Wcb   = (const float*)d_in[11];

  char* ws = (char*)d_ws;
  u16* nodes_bf = (u16*)(ws + 0);
  u16* last_bf  = (u16*)(ws + 8388608);
  u16* Qbuf     = (u16*)(ws + 16777216);
  u16* Kbuf     = (u16*)(ws + 25165824);
  u16* Vbuf     = (u16*)(ws + 33554432);
  u16* Obuf     = (u16*)(ws + 41943040);
  u16* mh_bf    = (u16*)(ws + 50331648);
  u16* Wkv_bf   = (u16*)(ws + 58720256);
  u16* Wq_bf    = (u16*)(ws + 58982400);
  u16* Wc_bf    = (u16*)(ws + 59113472);
  float* wq_lc  = (float*)(ws + 59244544);

  float* out = (float*)d_out;

  convert_kernel<<<4225, 256, 0, stream>>>(nodes, last, Wk, Wv, Wq, Wc,
                                           nodes_bf, last_bf, Wkv_bf, Wq_bf,
                                           wq_lc, Wc_bf);
  gemm_kv_kernel<<<2048, 256, 0, stream>>>(nodes_bf, Wkv_bf, Kbuf, Vbuf);
  gemm_q_kernel<<<1024, 256, 0, stream>>>(last_bf, Wq_bf, wq_lc, loadv, Qbuf);
  attn_kernel<<<1024, 256, 0, stream>>>(Qbuf, Kbuf, Vbuf, Obuf);
  gemm_c_kernel<<<1024, 256, 0, stream>>>(Obuf, Wc_bf, Wcb, mh_bf);
  s2_fused_kernel<<<1024, 256, 0, stream>>>(mh_bf, nodes_bf, cdist, ninf, out);
}